// Round 5
// baseline (459.695 us; speedup 1.0000x reference)
//
#include <hip/hip_runtime.h>
#include <hip/hip_bf16.h>
#include <stdint.h>
#include <float.h>

// VQ quantize: z[65536,256] f32, weight[1024,256] f32.
// ref (numpy fp32): d = fl32(fl32(A - 2*B) + C); idx = argmax(-d) (first-index ties).
// Outputs (float32, concat): quantized [65536*256], indices [65536].
//
// Pipeline:
//   1) to_bf16: z,w -> bf16 copies (scratch inside d_out; dead before gather)
//   2) rownorm_np: C=|w|^2 in exact numpy pairwise order
//   3) vq_screen: bf16 MFMA GEMM screen, flag rows with margin < TAU
//   4) vq_refine: flagged rows re-decided with bit-exact numpy-fp32 simulation
//      (pairwise A, sequential-k fma chain B). R5: register-blocked 2 rows x
//      4 codes/thread (8 independent chains), W read from L2 directly, z in
//      LDS; 3 barriers/batch instead of 67. Round-4 version was LDS-bound.
//   5) vq_gather.

constexpr int NROWS = 65536;
constexpr int D     = 256;
constexpr int CODES = 1024;

constexpr float TAU_SCREEN = 2.5e-4f;

typedef __attribute__((ext_vector_type(8))) short short8;   // 8 bf16 = 4 VGPR
typedef __attribute__((ext_vector_type(4))) float f32x4;

// ---------------- init ----------------
__global__ void init_ws(int* cnt) { if (threadIdx.x == 0) *cnt = 0; }

// ---------------- fp32 -> bf16 (RNE) ----------------
__device__ __forceinline__ unsigned short f2bf(float x) {
    union { __hip_bfloat16 h; unsigned short u; } c;
    c.h = __float2bfloat16(x);
    return c.u;
}

__global__ __launch_bounds__(256) void to_bf16(const float* __restrict__ src,
                                               unsigned short* __restrict__ dst,
                                               int n8) {
    const int i = blockIdx.x * 256 + threadIdx.x;
    if (i >= n8) return;
    const float4* s = (const float4*)src + (size_t)i * 2;
    float4 a = s[0], b = s[1];
    union { unsigned short u[8]; uint4 v; } p;
    p.u[0] = f2bf(a.x); p.u[1] = f2bf(a.y); p.u[2] = f2bf(a.z); p.u[3] = f2bf(a.w);
    p.u[4] = f2bf(b.x); p.u[5] = f2bf(b.y); p.u[6] = f2bf(b.z); p.u[7] = f2bf(b.w);
    *(uint4*)(dst + (size_t)i * 8) = p.v;
}

// ---------------- exact numpy pairwise |row|^2 ----------------
__device__ __forceinline__ float np_pairwise_sq256(const float* a) {
    float res[2];
    #pragma unroll
    for (int b = 0; b < 2; ++b) {
        float r[8];
        #pragma unroll
        for (int j = 0; j < 8; ++j) r[j] = 0.f;
        #pragma unroll
        for (int m = 0; m < 16; ++m) {
            const int base = b * 128 + m * 8;
            #pragma unroll
            for (int j = 0; j < 8; ++j)
                r[j] = __fadd_rn(r[j], __fmul_rn(a[base + j], a[base + j]));
        }
        res[b] = __fadd_rn(__fadd_rn(__fadd_rn(r[0], r[1]), __fadd_rn(r[2], r[3])),
                           __fadd_rn(__fadd_rn(r[4], r[5]), __fadd_rn(r[6], r[7])));
    }
    return __fadd_rn(res[0], res[1]);
}

__global__ __launch_bounds__(256) void rownorm_np(const float* __restrict__ x,
                                                  float* __restrict__ out, int nrows) {
    const int row = blockIdx.x * 256 + threadIdx.x;
    if (row >= nrows) return;
    float a[256];
    const float4* p = (const float4*)(x + (size_t)row * D);
    #pragma unroll
    for (int k4 = 0; k4 < 64; ++k4) {
        float4 v = p[k4];
        a[k4 * 4 + 0] = v.x; a[k4 * 4 + 1] = v.y;
        a[k4 * 4 + 2] = v.z; a[k4 * 4 + 3] = v.w;
    }
    out[row] = np_pairwise_sq256(a);
}

// ---------------- bf16 MFMA screen (unchanged from round 4) ----------------
__global__ __launch_bounds__(256, 2) void vq_screen(const unsigned short* __restrict__ zbf,
                                                    const unsigned short* __restrict__ wbf,
                                                    const float* __restrict__ Cn,
                                                    int* __restrict__ idx_out,
                                                    int* __restrict__ flagged,
                                                    int* __restrict__ cnt) {
    __shared__ unsigned short zT[128 * 64];
    __shared__ unsigned short wT[128 * 64];
    __shared__ float Cs[1024];
    __shared__ float rm1s[2][128];
    __shared__ float rm2s[2][128];
    __shared__ int   ris[2][128];

    const int t    = threadIdx.x;
    const int wv   = t >> 6;
    const int l    = t & 63;
    const int wm   = wv >> 1;
    const int wn   = wv & 1;
    const int m    = l & 15;
    const int quad = l >> 4;
    const int row0 = blockIdx.x * 128;

    for (int i = t; i < 1024; i += 256) Cs[i] = Cn[i];

    float m1[4][4], m2[4][4];
    int   bi[4][4];
    #pragma unroll
    for (int mi = 0; mi < 4; ++mi)
        #pragma unroll
        for (int r = 0; r < 4; ++r) { m1[mi][r] = FLT_MAX; m2[mi][r] = FLT_MAX; bi[mi][r] = 0; }

    const int sr  = t & 127;
    const int ssw = sr & 7;

    for (int nb = 0; nb < 8; ++nb) {
        f32x4 acc[4][4];
        #pragma unroll
        for (int mi = 0; mi < 4; ++mi)
            #pragma unroll
            for (int ni = 0; ni < 4; ++ni) acc[mi][ni] = (f32x4){0.f, 0.f, 0.f, 0.f};

        for (int ks = 0; ks < 4; ++ks) {
            __syncthreads();
            {
                const unsigned short* src = (t < 128)
                    ? zbf + ((size_t)(row0 + sr) * D + ks * 64)
                    : wbf + ((size_t)(nb * 128 + sr) * D + ks * 64);
                unsigned short* dst = (t < 128) ? &zT[sr * 64] : &wT[sr * 64];
                #pragma unroll
                for (int c = 0; c < 8; ++c) {
                    uint4 v = *(const uint4*)(src + c * 8);
                    *(uint4*)(dst + ((c ^ ssw) * 8)) = v;
                }
            }
            __syncthreads();
            #pragma unroll
            for (int kk = 0; kk < 2; ++kk) {
                short8 a[4], b[4];
                const int ch = kk * 4 + quad;
                #pragma unroll
                for (int mi = 0; mi < 4; ++mi) {
                    const int rr = wm * 64 + mi * 16 + m;
                    a[mi] = *(const short8*)&zT[rr * 64 + ((ch ^ (m & 7)) * 8)];
                }
                #pragma unroll
                for (int ni = 0; ni < 4; ++ni) {
                    const int rr = wn * 64 + ni * 16 + m;
                    b[ni] = *(const short8*)&wT[rr * 64 + ((ch ^ (m & 7)) * 8)];
                }
                #pragma unroll
                for (int mi = 0; mi < 4; ++mi)
                    #pragma unroll
                    for (int ni = 0; ni < 4; ++ni)
                        acc[mi][ni] = __builtin_amdgcn_mfma_f32_16x16x32_bf16(
                            a[mi], b[ni], acc[mi][ni], 0, 0, 0);
            }
        }
        #pragma unroll
        for (int ni = 0; ni < 4; ++ni) {
            const int code = nb * 128 + wn * 64 + ni * 16 + m;
            const float c  = Cs[code];
            #pragma unroll
            for (int mi = 0; mi < 4; ++mi)
                #pragma unroll
                for (int r = 0; r < 4; ++r) {
                    const float v = fmaf(-2.0f, acc[mi][ni][r], c);
                    if (v < m1[mi][r]) { m2[mi][r] = m1[mi][r]; m1[mi][r] = v; bi[mi][r] = code; }
                    else if (v < m2[mi][r]) m2[mi][r] = v;
                }
        }
    }

    #pragma unroll
    for (int mi = 0; mi < 4; ++mi)
        #pragma unroll
        for (int r = 0; r < 4; ++r) {
            float a1 = m1[mi][r], a2 = m2[mi][r];
            int   ai = bi[mi][r];
            #pragma unroll
            for (int off = 1; off <= 8; off <<= 1) {
                float o1 = __shfl_xor(a1, off, 64);
                float o2 = __shfl_xor(a2, off, 64);
                int   oi = __shfl_xor(ai, off, 64);
                float n2 = fminf(a2, o2);
                if (o1 < a1) { n2 = fminf(n2, a1); a1 = o1; ai = oi; }
                else n2 = fminf(n2, o1);
                a2 = n2;
            }
            m1[mi][r] = a1; m2[mi][r] = a2; bi[mi][r] = ai;
        }

    if (m == 0) {
        #pragma unroll
        for (int mi = 0; mi < 4; ++mi)
            #pragma unroll
            for (int r = 0; r < 4; ++r) {
                const int rl = wm * 64 + mi * 16 + quad * 4 + r;
                rm1s[wn][rl] = m1[mi][r];
                rm2s[wn][rl] = m2[mi][r];
                ris[wn][rl]  = bi[mi][r];
            }
    }
    __syncthreads();
    if (t < 128) {
        float a1 = rm1s[0][t], a2 = rm2s[0][t];
        int   ai = ris[0][t];
        const float o1 = rm1s[1][t], o2 = rm2s[1][t];
        const int   oi = ris[1][t];
        float n2 = fminf(a2, o2);
        if (o1 < a1) { n2 = fminf(n2, a1); a1 = o1; ai = oi; }
        else n2 = fminf(n2, o1);
        a2 = n2;
        const int row = row0 + t;
        idx_out[row] = ai;
        if (a2 - a1 < TAU_SCREEN) {
            int p = atomicAdd(cnt, 1);
            flagged[p] = row;
        }
    }
}

// ---------------- exact numpy-sim refine, register-blocked ----------------
// batch = 8 rows x 1024 codes; thread owns 2 rows x 4 codes (8 independent
// sequential-k fmaf chains). z in LDS (stride 260 -> conflict-free 4-addr
// broadcast reads); w read directly from global (1 MB, L2-resident).
constexpr int R_RB = 8;

__global__ __launch_bounds__(256) void vq_refine(const float* __restrict__ z,
                                                 const float* __restrict__ w,
                                                 const float* __restrict__ Cn,
                                                 const int* __restrict__ flagged,
                                                 const int* __restrict__ cnt,
                                                 int* __restrict__ idx_out) {
    __shared__ float zl[R_RB][260];
    __shared__ float sAr[R_RB];
    __shared__ int   rowids[R_RB];
    __shared__ float redd[R_RB][66];
    __shared__ int   redi[R_RB][66];

    const int t  = threadIdx.x;
    const int rg = (t >> 4) & 3;                 // rows rg*2, rg*2+1
    const int cg = (t & 15) + (t >> 6) * 16;     // code group 0..63 (4 codes each)
    const int n  = *cnt;
    const int nbatch = (n + R_RB - 1) / R_RB;
    const float4* wp = (const float4*)w;

    for (int batch = blockIdx.x; batch < nbatch; batch += gridDim.x) {
        __syncthreads();                         // protect zl/red reuse
        if (t < R_RB) {
            const int fi = batch * R_RB + t;
            rowids[t] = (fi < n) ? flagged[fi] : -1;
        }
        __syncthreads();
        for (int i = t; i < R_RB * 64; i += 256) {
            const int r = i >> 6, k4 = i & 63;
            const int row = rowids[r];
            float4 v = make_float4(0.f, 0.f, 0.f, 0.f);
            if (row >= 0) v = ((const float4*)(z + (size_t)row * D))[k4];
            *(float4*)&zl[r][k4 * 4] = v;
        }
        __syncthreads();
        if (t < R_RB) sAr[t] = np_pairwise_sq256(zl[t]);   // exact numpy A
        __syncthreads();

        float bd0 = FLT_MAX, bd1 = FLT_MAX;
        int   bi0 = 0,       bi1 = 0;
        const float A0 = sAr[rg * 2 + 0];
        const float A1 = sAr[rg * 2 + 1];

        for (int c0 = 0; c0 < CODES; c0 += 256) {
            const int cbase = c0 + cg * 4;
            float B0[4] = {0.f, 0.f, 0.f, 0.f};
            float B1[4] = {0.f, 0.f, 0.f, 0.f};
            #pragma unroll 8
            for (int k4 = 0; k4 < 64; ++k4) {
                const float4 z0 = *(const float4*)&zl[rg * 2 + 0][k4 * 4];
                const float4 z1 = *(const float4*)&zl[rg * 2 + 1][k4 * 4];
                #pragma unroll
                for (int j = 0; j < 4; ++j) {
                    const float4 wv = wp[(size_t)(cbase + j) * 64 + k4];
                    B0[j] = fmaf(z0.x, wv.x, B0[j]);
                    B0[j] = fmaf(z0.y, wv.y, B0[j]);
                    B0[j] = fmaf(z0.z, wv.z, B0[j]);
                    B0[j] = fmaf(z0.w, wv.w, B0[j]);
                    B1[j] = fmaf(z1.x, wv.x, B1[j]);
                    B1[j] = fmaf(z1.y, wv.y, B1[j]);
                    B1[j] = fmaf(z1.z, wv.z, B1[j]);
                    B1[j] = fmaf(z1.w, wv.w, B1[j]);
                }
            }
            #pragma unroll
            for (int j = 0; j < 4; ++j) {
                const int code = cbase + j;
                const float C = Cn[code];
                const float d0 = __fadd_rn(__fsub_rn(A0, __fmul_rn(2.0f, B0[j])), C);
                const float d1 = __fadd_rn(__fsub_rn(A1, __fmul_rn(2.0f, B1[j])), C);
                if (d0 < bd0) { bd0 = d0; bi0 = code; }   // ascending code order
                if (d1 < bd1) { bd1 = d1; bi1 = code; }
            }
        }
        redd[rg * 2 + 0][cg] = bd0; redi[rg * 2 + 0][cg] = bi0;
        redd[rg * 2 + 1][cg] = bd1; redi[rg * 2 + 1][cg] = bi1;
        __syncthreads();
        if (t < R_RB) {
            const int row = rowids[t];
            if (row >= 0) {
                float best = redd[t][0];
                int   bidx = redi[t][0];
                for (int c = 1; c < 64; ++c) {
                    const float d = redd[t][c];
                    const int   i = redi[t][c];
                    if (d < best || (d == best && i < bidx)) { best = d; bidx = i; }
                }
                idx_out[row] = bidx;
            }
        }
    }
}

// ---------------- gather ----------------
__global__ __launch_bounds__(256) void vq_gather(const float* __restrict__ w,
                                                 const int* __restrict__ idx,
                                                 float* __restrict__ outq,
                                                 float* __restrict__ outi) {
    const int t    = threadIdx.x;
    const int lane = t & 63;
    const int sub  = t >> 6;
    const int row0 = blockIdx.x * 128;
    #pragma unroll 4
    for (int it = 0; it < 32; ++it) {
        const int row = row0 + it * 4 + sub;
        const int j   = idx[row];
        ((float4*)outq)[(size_t)row * 64 + lane] = ((const float4*)w)[(size_t)j * 64 + lane];
        if (lane == 0) outi[row] = (float)j;
    }
}

extern "C" void kernel_launch(void* const* d_in, const int* in_sizes, int n_in,
                              void* d_out, int out_size, void* d_ws, size_t ws_size,
                              hipStream_t stream) {
    const float* z = (const float*)d_in[0];
    const float* w = (const float*)d_in[1];
    float* outq = (float*)d_out;
    float* outi = outq + (size_t)NROWS * D;

    // scratch inside d_out (dead before vq_gather overwrites it):
    //   zbf [0, 32MB) | wbf [32MB, +512KB) | Cn [+4KB)
    unsigned short* zbf = (unsigned short*)d_out;
    unsigned short* wbf = (unsigned short*)((char*)d_out + 33554432);
    float*          Cn  = (float*)((char*)d_out + 34078720);

    char* ws      = (char*)d_ws;
    int*  idx     = (int*)ws;
    int*  flagged = (int*)(ws + 262144);
    int*  cnt     = (int*)(ws + 524288);

    init_ws<<<1, 64, 0, stream>>>(cnt);
    to_bf16<<<NROWS * D / 8 / 256, 256, 0, stream>>>(z, zbf, NROWS * D / 8);
    to_bf16<<<CODES * D / 8 / 256, 256, 0, stream>>>(w, wbf, CODES * D / 8);
    rownorm_np<<<(CODES + 255) / 256, 256, 0, stream>>>(w, Cn, CODES);
    vq_screen<<<NROWS / 128, 256, 0, stream>>>(zbf, wbf, Cn, idx, flagged, cnt);
    vq_refine<<<2048, 256, 0, stream>>>(z, w, Cn, flagged, cnt, idx);
    vq_gather<<<NROWS / 128, 256, 0, stream>>>(w, idx, outq, outi);
}

// Round 6
// 389.679 us; speedup vs baseline: 1.1797x; 1.1797x over previous
//
#include <hip/hip_runtime.h>
#include <hip/hip_bf16.h>
#include <stdint.h>
#include <float.h>

// VQ quantize: z[65536,256] f32, weight[1024,256] f32.
// ref (numpy fp32): d = fl32(fl32(A - 2*B) + C); idx = argmax(-d) (first-index ties).
// Outputs (float32, concat): quantized [65536*256], indices [65536].
//
// R6 pipeline:
//   1) to_frag: z,w -> bf16 in MFMA A-fragment-linear layout [g][ch][lane][8]
//      (scratch inside d_out; dead until gather).
//   2) rownorm_np: C=|w|^2 exact numpy pairwise (proven bit-exact).
//   3) vq_screen: MFMA screen, A staged LDS lane-linear (conflict-free),
//      B streamed global->VGPR (L2). Writes idx, smin, flagged, inits key.
//   4) compact_frags: gather flagged rows' fragments into zc.
//   5) cand_screen: bit-identical MFMA re-score of flagged rows; emit codes
//      with v <= smin+TAU (contains sim-argmin when 2E <= TAU -- same proven
//      condition as rounds 4/5).
//   6) exact_eval: per candidate, exact numpy-sim d (pairwise A + sequential-k
//      fmaf B); atomicMin key[row] with (bits(d)<<32 | code) -> min d, tie min code.
//   7) writeback flagged idx; 8) vq_gather.

constexpr int NROWS = 65536;
constexpr int D     = 256;
constexpr int CODES = 1024;
constexpr float TAU_SCREEN = 2.5e-4f;
constexpr int ZC_CAP   = 32768;     // max refined rows (expect ~6k)
constexpr int CAND_CAP = 262144;    // max candidates (expect ~13k)

typedef __attribute__((ext_vector_type(8))) short short8;   // 8 bf16 = 4 VGPR
typedef __attribute__((ext_vector_type(4))) float f32x4;
typedef unsigned long long u64;

// ---------------- init ----------------
__global__ void init_ws(int* cnt, int* ccnt) {
    if (threadIdx.x == 0) { *cnt = 0; *ccnt = 0; }
}

__device__ __forceinline__ unsigned short f2bf(float x) {
    union { __hip_bfloat16 h; unsigned short u; } c;
    c.h = __float2bfloat16(x);
    return c.u;
}

// ---------------- fp32 -> bf16 fragment-linear layout ----------------
// chunk f: l=f&63, ch=(f>>6)&7, g=f>>9; lane l = (quad=l>>4, m=l&15);
// data = src[row=g*16+m][k = ch*32 + quad*8 .. +8]
__global__ __launch_bounds__(256) void to_frag(const float* __restrict__ src,
                                               uint4* __restrict__ dst, int ngroups) {
    const int f = blockIdx.x * 256 + threadIdx.x;
    if (f >= ngroups * 512) return;
    const int l  = f & 63;
    const int ch = (f >> 6) & 7;
    const int g  = f >> 9;
    const int m = l & 15, quad = l >> 4;
    const float4* p = (const float4*)(src + (size_t)(g * 16 + m) * D + ch * 32 + quad * 8);
    float4 a = p[0], b = p[1];
    union { unsigned short u[8]; uint4 v; } pk;
    pk.u[0] = f2bf(a.x); pk.u[1] = f2bf(a.y); pk.u[2] = f2bf(a.z); pk.u[3] = f2bf(a.w);
    pk.u[4] = f2bf(b.x); pk.u[5] = f2bf(b.y); pk.u[6] = f2bf(b.z); pk.u[7] = f2bf(b.w);
    dst[f] = pk.v;
}

// ---------------- exact numpy pairwise |row|^2 ----------------
__device__ __forceinline__ float np_pairwise_sq256(const float* a) {
    float res[2];
    #pragma unroll
    for (int b = 0; b < 2; ++b) {
        float r[8];
        #pragma unroll
        for (int j = 0; j < 8; ++j) r[j] = 0.f;
        #pragma unroll
        for (int m = 0; m < 16; ++m) {
            const int base = b * 128 + m * 8;
            #pragma unroll
            for (int j = 0; j < 8; ++j)
                r[j] = __fadd_rn(r[j], __fmul_rn(a[base + j], a[base + j]));
        }
        res[b] = __fadd_rn(__fadd_rn(__fadd_rn(r[0], r[1]), __fadd_rn(r[2], r[3])),
                           __fadd_rn(__fadd_rn(r[4], r[5]), __fadd_rn(r[6], r[7])));
    }
    return __fadd_rn(res[0], res[1]);
}

__global__ __launch_bounds__(256) void rownorm_np(const float* __restrict__ x,
                                                  float* __restrict__ out, int nrows) {
    const int row = blockIdx.x * 256 + threadIdx.x;
    if (row >= nrows) return;
    float a[256];
    const float4* p = (const float4*)(x + (size_t)row * D);
    #pragma unroll
    for (int k4 = 0; k4 < 64; ++k4) {
        float4 v = p[k4];
        a[k4 * 4 + 0] = v.x; a[k4 * 4 + 1] = v.y;
        a[k4 * 4 + 2] = v.z; a[k4 * 4 + 3] = v.w;
    }
    out[row] = np_pairwise_sq256(a);
}

// ---------------- MFMA screen, fragment-linear ----------------
// block = 128 rows x 1024 codes; 4 waves (wm x wn 2x2), wave 64x64 per nb.
__global__ __launch_bounds__(256, 2) void vq_screen(const uint4* __restrict__ zf,
                                                    const short8* __restrict__ wf8,
                                                    const float* __restrict__ Cn,
                                                    int* __restrict__ idx_out,
                                                    float* __restrict__ smin,
                                                    u64* __restrict__ key,
                                                    int* __restrict__ flagged,
                                                    int* __restrict__ cnt) {
    __shared__ uint4 Ald[4096];          // 8 groups * 8 ch * 64 lanes (64 KB)
    __shared__ float Cs[1024];
    __shared__ float rm1s[2][128];
    __shared__ float rm2s[2][128];
    __shared__ int   ris[2][128];

    const int t    = threadIdx.x;
    const int wv   = t >> 6;
    const int l    = t & 63;
    const int wm   = wv >> 1;
    const int wn   = wv & 1;
    const int m    = l & 15;
    const int quad = l >> 4;
    const int row0 = blockIdx.x * 128;
    const size_t g0 = (size_t)(row0 >> 4) * 512;

    for (int i = t; i < 4096; i += 256) Ald[i] = zf[g0 + i];   // lane-linear: conflict-free
    for (int i = t; i < 1024; i += 256) Cs[i] = Cn[i];
    __syncthreads();

    float m1[4][4], m2[4][4];
    int   bi[4][4];
    #pragma unroll
    for (int mi = 0; mi < 4; ++mi)
        #pragma unroll
        for (int r = 0; r < 4; ++r) { m1[mi][r] = FLT_MAX; m2[mi][r] = FLT_MAX; bi[mi][r] = 0; }

    for (int nb = 0; nb < 8; ++nb) {
        f32x4 acc[4][4];
        #pragma unroll
        for (int mi = 0; mi < 4; ++mi)
            #pragma unroll
            for (int ni = 0; ni < 4; ++ni) acc[mi][ni] = (f32x4){0.f, 0.f, 0.f, 0.f};

        #pragma unroll
        for (int ch = 0; ch < 8; ++ch) {
            short8 a[4], b[4];
            #pragma unroll
            for (int ni = 0; ni < 4; ++ni) {
                const int gg = nb * 8 + wn * 4 + ni;
                b[ni] = wf8[(size_t)((gg * 8 + ch) * 64 + l)];
            }
            #pragma unroll
            for (int mi = 0; mi < 4; ++mi)
                a[mi] = *(const short8*)&Ald[((wm * 4 + mi) * 8 + ch) * 64 + l];
            #pragma unroll
            for (int mi = 0; mi < 4; ++mi)
                #pragma unroll
                for (int ni = 0; ni < 4; ++ni)
                    acc[mi][ni] = __builtin_amdgcn_mfma_f32_16x16x32_bf16(
                        a[mi], b[ni], acc[mi][ni], 0, 0, 0);
        }
        #pragma unroll
        for (int ni = 0; ni < 4; ++ni) {
            const int code = nb * 128 + wn * 64 + ni * 16 + m;
            const float c  = Cs[code];
            #pragma unroll
            for (int mi = 0; mi < 4; ++mi)
                #pragma unroll
                for (int r = 0; r < 4; ++r) {
                    const float v = fmaf(-2.0f, acc[mi][ni][r], c);
                    if (v < m1[mi][r]) { m2[mi][r] = m1[mi][r]; m1[mi][r] = v; bi[mi][r] = code; }
                    else if (v < m2[mi][r]) m2[mi][r] = v;
                }
        }
    }

    #pragma unroll
    for (int mi = 0; mi < 4; ++mi)
        #pragma unroll
        for (int r = 0; r < 4; ++r) {
            float a1 = m1[mi][r], a2 = m2[mi][r];
            int   ai = bi[mi][r];
            #pragma unroll
            for (int off = 1; off <= 8; off <<= 1) {
                float o1 = __shfl_xor(a1, off, 64);
                float o2 = __shfl_xor(a2, off, 64);
                int   oi = __shfl_xor(ai, off, 64);
                float n2 = fminf(a2, o2);
                if (o1 < a1) { n2 = fminf(n2, a1); a1 = o1; ai = oi; }
                else n2 = fminf(n2, o1);
                a2 = n2;
            }
            m1[mi][r] = a1; m2[mi][r] = a2; bi[mi][r] = ai;
        }

    if (m == 0) {
        #pragma unroll
        for (int mi = 0; mi < 4; ++mi)
            #pragma unroll
            for (int r = 0; r < 4; ++r) {
                const int rl = wm * 64 + mi * 16 + quad * 4 + r;
                rm1s[wn][rl] = m1[mi][r];
                rm2s[wn][rl] = m2[mi][r];
                ris[wn][rl]  = bi[mi][r];
            }
    }
    __syncthreads();
    if (t < 128) {
        float a1 = rm1s[0][t], a2 = rm2s[0][t];
        int   ai = ris[0][t];
        const float o1 = rm1s[1][t], o2 = rm2s[1][t];
        const int   oi = ris[1][t];
        float n2 = fminf(a2, o2);
        if (o1 < a1) { n2 = fminf(n2, a1); a1 = o1; ai = oi; }
        else n2 = fminf(n2, o1);
        a2 = n2;
        const int row = row0 + t;
        idx_out[row] = ai;
        smin[row] = a1;
        if (a2 - a1 < TAU_SCREEN) {
            key[row] = ~0ull;
            int p = atomicAdd(cnt, 1);
            if (p < NROWS) flagged[p] = row;
        }
    }
}

// ---------------- compact flagged rows' fragments ----------------
__global__ __launch_bounds__(256) void compact_frags(const uint4* __restrict__ zf,
                                                     uint4* __restrict__ zc,
                                                     const int* __restrict__ flagged,
                                                     const int* __restrict__ cnt) {
    const int i = blockIdx.x * 256 + threadIdx.x;     // over ZC_CAP*32 chunks
    const int n = min(*cnt, ZC_CAP);
    const int fi = i >> 5;
    if (fi >= n) return;
    const int sub = i & 31, ch = sub >> 2, quad = sub & 3;
    const int row = flagged[fi];
    const int g = row >> 4, m = row & 15;
    const int gg = fi >> 4, mm = fi & 15;
    zc[(size_t)(gg * 8 + ch) * 64 + quad * 16 + mm] =
        zf[(size_t)(g * 8 + ch) * 64 + quad * 16 + m];
}

// ---------------- candidate collection (bit-identical MFMA re-score) ----------------
__global__ __launch_bounds__(256, 1) void cand_screen(const short8* __restrict__ zc8,
                                                      const short8* __restrict__ wf8,
                                                      const float* __restrict__ Cn,
                                                      const float* __restrict__ smin,
                                                      const int* __restrict__ flagged,
                                                      const int* __restrict__ cnt,
                                                      u64* __restrict__ cand,
                                                      int* __restrict__ ccnt) {
    __shared__ float thrs[128];
    __shared__ int   rows_s[128];
    __shared__ float Cs[1024];

    const int n = min(*cnt, ZC_CAP);
    const int b = blockIdx.x;
    if (b * 128 >= n) return;

    const int t    = threadIdx.x;
    const int wv   = t >> 6;
    const int l    = t & 63;
    const int wm   = wv >> 1;
    const int wn   = wv & 1;
    const int m    = l & 15;
    const int quad = l >> 4;

    if (t < 128) {
        const int fi = b * 128 + t;
        const int row = (fi < n) ? flagged[fi] : -1;
        rows_s[t] = row;
        thrs[t] = (row >= 0) ? (smin[row] + TAU_SCREEN) : -FLT_MAX;
    }
    for (int i = t; i < 1024; i += 256) Cs[i] = Cn[i];
    __syncthreads();

    short8 A[4][8];
    #pragma unroll
    for (int mi = 0; mi < 4; ++mi)
        #pragma unroll
        for (int ch = 0; ch < 8; ++ch) {
            const int gc = b * 8 + wm * 4 + mi;
            A[mi][ch] = zc8[(size_t)(gc * 8 + ch) * 64 + l];
        }

    for (int nb = 0; nb < 8; ++nb) {
        f32x4 acc[4][4];
        #pragma unroll
        for (int mi = 0; mi < 4; ++mi)
            #pragma unroll
            for (int ni = 0; ni < 4; ++ni) acc[mi][ni] = (f32x4){0.f, 0.f, 0.f, 0.f};
        #pragma unroll
        for (int ch = 0; ch < 8; ++ch) {
            short8 bfr[4];
            #pragma unroll
            for (int ni = 0; ni < 4; ++ni) {
                const int gg = nb * 8 + wn * 4 + ni;
                bfr[ni] = wf8[(size_t)((gg * 8 + ch) * 64 + l)];
            }
            #pragma unroll
            for (int mi = 0; mi < 4; ++mi)
                #pragma unroll
                for (int ni = 0; ni < 4; ++ni)
                    acc[mi][ni] = __builtin_amdgcn_mfma_f32_16x16x32_bf16(
                        A[mi][ch], bfr[ni], acc[mi][ni], 0, 0, 0);
        }
        #pragma unroll
        for (int ni = 0; ni < 4; ++ni) {
            const int code = nb * 128 + wn * 64 + ni * 16 + m;
            const float c  = Cs[code];
            #pragma unroll
            for (int mi = 0; mi < 4; ++mi)
                #pragma unroll
                for (int r = 0; r < 4; ++r) {
                    const float v = fmaf(-2.0f, acc[mi][ni][r], c);
                    const int rl = wm * 64 + mi * 16 + quad * 4 + r;
                    if (v <= thrs[rl]) {
                        const int row = rows_s[rl];
                        if (row >= 0) {
                            int p = atomicAdd(ccnt, 1);
                            if (p < CAND_CAP)
                                cand[p] = ((u64)(unsigned)row << 32) | (unsigned)code;
                        }
                    }
                }
        }
    }
}

// ---------------- exact numpy-sim per candidate ----------------
__global__ __launch_bounds__(256) void exact_eval(const float* __restrict__ z,
                                                  const float* __restrict__ w,
                                                  const float* __restrict__ Cn,
                                                  const u64* __restrict__ cand,
                                                  const int* __restrict__ ccnt,
                                                  u64* __restrict__ key) {
    const int ci = blockIdx.x * 256 + threadIdx.x;
    const int nc = min(*ccnt, CAND_CAP);
    if (ci >= nc) return;
    const u64 c = cand[ci];
    const int row  = (int)(c >> 32);
    const int code = (int)(c & 0xffffffffu);
    const float4* zp = (const float4*)(z + (size_t)row * D);
    const float4* wp = (const float4*)(w + (size_t)code * D);

    // exact numpy pairwise A (streamed, no local array)
    float res[2];
    #pragma unroll
    for (int bb = 0; bb < 2; ++bb) {
        float r[8];
        #pragma unroll
        for (int j = 0; j < 8; ++j) r[j] = 0.f;
        #pragma unroll
        for (int mm = 0; mm < 16; ++mm) {
            const float4 x = zp[bb * 32 + mm * 2];
            const float4 y = zp[bb * 32 + mm * 2 + 1];
            r[0] = __fadd_rn(r[0], __fmul_rn(x.x, x.x));
            r[1] = __fadd_rn(r[1], __fmul_rn(x.y, x.y));
            r[2] = __fadd_rn(r[2], __fmul_rn(x.z, x.z));
            r[3] = __fadd_rn(r[3], __fmul_rn(x.w, x.w));
            r[4] = __fadd_rn(r[4], __fmul_rn(y.x, y.x));
            r[5] = __fadd_rn(r[5], __fmul_rn(y.y, y.y));
            r[6] = __fadd_rn(r[6], __fmul_rn(y.z, y.z));
            r[7] = __fadd_rn(r[7], __fmul_rn(y.w, y.w));
        }
        res[bb] = __fadd_rn(__fadd_rn(__fadd_rn(r[0], r[1]), __fadd_rn(r[2], r[3])),
                            __fadd_rn(__fadd_rn(r[4], r[5]), __fadd_rn(r[6], r[7])));
    }
    const float A = __fadd_rn(res[0], res[1]);

    // B: sequential fp32 fma chain, ascending k (sgemm microkernel order)
    float B = 0.f;
    #pragma unroll 8
    for (int k4 = 0; k4 < 64; ++k4) {
        const float4 x = zp[k4];
        const float4 v = wp[k4];
        B = fmaf(x.x, v.x, B);
        B = fmaf(x.y, v.y, B);
        B = fmaf(x.z, v.z, B);
        B = fmaf(x.w, v.w, B);
    }
    const float d = __fadd_rn(__fsub_rn(A, __fmul_rn(2.0f, B)), Cn[code]);
    const u64 k = ((u64)__float_as_uint(d) << 32) | (unsigned)code;   // d > 0 always
    atomicMin((unsigned long long*)&key[row], (unsigned long long)k);
}

__global__ __launch_bounds__(256) void writeback(const int* __restrict__ flagged,
                                                 const int* __restrict__ cnt,
                                                 const u64* __restrict__ key,
                                                 int* __restrict__ idx_out) {
    const int fi = blockIdx.x * 256 + threadIdx.x;
    const int n = min(*cnt, NROWS);
    if (fi >= n) return;
    const int row = flagged[fi];
    const u64 k = key[row];
    if (k != ~0ull) idx_out[row] = (int)(k & 0xffffffffu);
}

// ---------------- gather ----------------
__global__ __launch_bounds__(256) void vq_gather(const float* __restrict__ w,
                                                 const int* __restrict__ idx,
                                                 float* __restrict__ outq,
                                                 float* __restrict__ outi) {
    const int t    = threadIdx.x;
    const int lane = t & 63;
    const int sub  = t >> 6;
    const int row0 = blockIdx.x * 128;
    #pragma unroll 4
    for (int it = 0; it < 32; ++it) {
        const int row = row0 + it * 4 + sub;
        const int j   = idx[row];
        ((float4*)outq)[(size_t)row * 64 + lane] = ((const float4*)w)[(size_t)j * 64 + lane];
        if (lane == 0) outi[row] = (float)j;
    }
}

extern "C" void kernel_launch(void* const* d_in, const int* in_sizes, int n_in,
                              void* d_out, int out_size, void* d_ws, size_t ws_size,
                              hipStream_t stream) {
    const float* z = (const float*)d_in[0];
    const float* w = (const float*)d_in[1];
    float* outq = (float*)d_out;
    float* outi = outq + (size_t)NROWS * D;

    // scratch inside d_out (all dead before vq_gather overwrites):
    char* ob = (char*)d_out;
    uint4* zf   = (uint4*)(ob + 0);            // 32 MB  frag-linear z bf16
    uint4* wf   = (uint4*)(ob + 33554432);     // 512 KB frag-linear w bf16
    float* Cn   = (float*)(ob + 34078720);     // 4 KB
    float* smin = (float*)(ob + 34082816);     // 256 KB
    u64*   key  = (u64*)  (ob + 34344960);     // 512 KB
    u64*   cand = (u64*)  (ob + 34869248);     // 2 MB
    uint4* zc   = (uint4*)(ob + 37748736);     // 16 MB compacted flagged frags

    char* ws      = (char*)d_ws;
    int*  idx     = (int*)ws;                  // 256 KB
    int*  flagged = (int*)(ws + 262144);       // 256 KB
    int*  cnt     = (int*)(ws + 524288);
    int*  ccnt    = (int*)(ws + 524292);

    init_ws<<<1, 64, 0, stream>>>(cnt, ccnt);
    to_frag<<<8192, 256, 0, stream>>>(z, zf, NROWS / 16);
    to_frag<<<128, 256, 0, stream>>>(w, wf, CODES / 16);
    rownorm_np<<<(CODES + 255) / 256, 256, 0, stream>>>(w, Cn, CODES);
    vq_screen<<<NROWS / 128, 256, 0, stream>>>(zf, (const short8*)wf, Cn,
                                               idx, smin, key, flagged, cnt);
    compact_frags<<<ZC_CAP * 32 / 256, 256, 0, stream>>>(zf, zc, flagged, cnt);
    cand_screen<<<ZC_CAP / 128, 256, 0, stream>>>((const short8*)zc, (const short8*)wf,
                                                  Cn, smin, flagged, cnt, cand, ccnt);
    exact_eval<<<CAND_CAP / 256, 256, 0, stream>>>(z, w, Cn, cand, ccnt, key);
    writeback<<<NROWS / 256, 256, 0, stream>>>(flagged, cnt, key, idx);
    vq_gather<<<NROWS / 128, 256, 0, stream>>>(w, idx, outq, outi);
}